// Round 9
// baseline (704.060 us; speedup 1.0000x reference)
//
#include <hip/hip_runtime.h>
#include <math.h>

#define TT 2048
#define BBATCH 256
#define DDIM 57
#define NF 524288.0f
#define U 8

#define K1 (-1.4426950408889634f)   // -log2(e)   : sigmoid rows (i,f,o)
#define K2 (-2.8853900817779268f)   // -2 log2(e) : tanh rows (g) and tanh(c)

__device__ __forceinline__ float bcastl(float v, int k) {
  return __uint_as_float((unsigned)__builtin_amdgcn_readlane((int)__float_as_uint(v), k));
}
__device__ __forceinline__ float rcpf(float x) { return __builtin_amdgcn_rcpf(x); }
__device__ __forceinline__ float exp2f_(float x) { return __builtin_amdgcn_exp2f(x); }

// quad_perm broadcast: all 4 lanes of each quad get lane (PAT&3)'s value.
template<int PAT>
__device__ __forceinline__ float quadb(float v) {
  return __int_as_float(__builtin_amdgcn_update_dpp(0, __float_as_int(v), PAT, 0xF, 0xF, true));
}

__global__ void zero_accum_k(float* accum) {
  accum[threadIdx.x] = 0.f;
}

// Fused: layer-pipelined scan (waves 0-2) + in-block xg producer (wave 3).
// Wave w (w<3) owns layer w, lagging w slots; U=8 steps/slot; one
// __syncthreads per slot. Wave3 pipeline: at slot s it (a) issues x-row
// loads for slot s+2 (one full slot of latency cover), (b) computes
// xg = fac*(W_ih0.x + b) for slot s+1 from rows loaded at s-1 (hoisted
// readlane broadcasts, off every other wave's critical chain), (c) stores
// to a 2-deep LDS buffer wave0 reads at slot start. This replaces the
// standalone gemm kernel and its 256 MB xg0 HBM round-trip.
__global__ __launch_bounds__(256, 1) void lstm_fused_k(
    const float* __restrict__ x,
    const int*   __restrict__ lengths,
    const float* __restrict__ Wih0, const float* __restrict__ Whh0,
    const float* __restrict__ bih0, const float* __restrict__ bhh0,
    const float* __restrict__ Wih1, const float* __restrict__ Whh1,
    const float* __restrict__ bih1, const float* __restrict__ bhh1,
    const float* __restrict__ Wih2, const float* __restrict__ Whh2,
    const float* __restrict__ bih2, const float* __restrict__ bhh2,
    float* __restrict__ h2buf, float* __restrict__ accum)
{
  const int tid  = threadIdx.x;
  const int wave = tid >> 6;       // 0,1,2 = layer; 3 = xg producer
  const int lane = tid & 63;
  const int gt   = lane & 3;       // 0=i 1=f 2=g 3=o
  const int ch   = lane >> 2;      // channel 0..15
  const int g    = gt*16 + ch;     // weight row (PyTorch i,f,g,o blocks)
  const int b    = blockIdx.x;
  const int len  = lengths[b];
  const bool isg = (gt == 2);
  const float fac = isg ? K2 : K1;
  const float mg = isg ? 2.f : 1.f;     // act = s*mg + ag
  const float ag = isg ? -1.f : 0.f;

  __shared__ float lds_h0[2][U][16];
  __shared__ float lds_h1[2][U][16];
  __shared__ float lds_xg[2][U][64];

  // waves 0-2 weights; wave3 input-projection weights
  float wa[16], wb[16];
  float bias = 0.f;
  float wx[DDIM];
  if (wave == 0) {
    #pragma unroll
    for (int k = 0; k < 16; ++k) { wb[k] = fac * Whh0[g*16 + k]; wa[k] = 0.f; }
  } else if (wave == 1) {
    #pragma unroll
    for (int k = 0; k < 16; ++k) { wa[k] = fac * Wih1[g*16 + k]; wb[k] = fac * Whh1[g*16 + k]; }
    bias = fac * (bih1[g] + bhh1[g]);
  } else if (wave == 2) {
    #pragma unroll
    for (int k = 0; k < 16; ++k) { wa[k] = fac * Wih2[g*16 + k]; wb[k] = fac * Whh2[g*16 + k]; }
    bias = fac * (bih2[g] + bhh2[g]);
  } else {
    #pragma unroll
    for (int d = 0; d < DDIM; ++d) wx[d] = fac * Wih0[g*DDIM + d];
    bias = fac * (bih0[g] + bhh0[g]);
  }

  float hs = 0.f, csK = 0.f;            // csK = K2 * c  (pre-scaled recurrence)
  float sum = 0.f, sq = 0.f;
  float* __restrict__ h2row = h2buf + (size_t)b*TT*16;
  const float* __restrict__ xseq = x + (size_t)b*TT*DDIM;

  auto lstm_update = [&](float dot) {
    float s   = rcpf(1.f + exp2f_(dot));
    float act = fmaf(s, mg, ag);          // sigmoid, or tanh for g-gate
    float gi = quadb<0x00>(act);
    float gf = quadb<0x55>(act);
    float gg = quadb<0xAA>(act);
    float go = quadb<0xFF>(act);
    csK = fmaf(gf, csK, (K2 * gg) * gi);  // K2*(f*c + i*g)
    float r = rcpf(1.f + exp2f_(csK));
    hs = go * fmaf(2.f, r, -1.f);         // go * tanh(c)
  };
  auto owndot = [&](float seed) {         // seed + Whh' . h_own
    float hb[16];                         // ALL broadcasts first
    #pragma unroll
    for (int k = 0; k < 16; ++k) hb[k] = bcastl(hs, 4*k);
    float a0 = seed, a1 = 0.f, a2 = 0.f, a3 = 0.f;
    #pragma unroll
    for (int k = 0; k < 16; k += 4) {
      a0 += wb[k]   * hb[k];
      a1 += wb[k+1] * hb[k+1];
      a2 += wb[k+2] * hb[k+2];
      a3 += wb[k+3] * hb[k+3];
    }
    return (a0 + a1) + (a2 + a3);
  };
  auto indot = [&](const float* hin) {    // bias + Wih' . hin (off-chain)
    float a0 = bias, a1 = 0.f, a2 = 0.f, a3 = 0.f;
    #pragma unroll
    for (int k = 0; k < 16; k += 4) {
      a0 += wa[k]   * hin[k];
      a1 += wa[k+1] * hin[k+1];
      a2 += wa[k+2] * hin[k+2];
      a3 += wa[k+3] * hin[k+3];
    }
    return (a0 + a1) + (a2 + a3);
  };
  // wave3: xg for one step from its x-row registers (broadcasts hoisted)
  auto xgdot = [&](float xv) {
    float xb[DDIM];
    #pragma unroll
    for (int d = 0; d < DDIM; ++d) xb[d] = bcastl(xv, d);
    float a0 = bias, a1 = 0.f, a2 = 0.f, a3 = 0.f;
    #pragma unroll
    for (int d = 0; d < 56; d += 4) {
      a0 += wx[d]   * xb[d];
      a1 += wx[d+1] * xb[d+1];
      a2 += wx[d+2] * xb[d+2];
      a3 += wx[d+3] * xb[d+3];
    }
    a0 += wx[56] * xb[56];
    return (a0 + a1) + (a2 + a3);
  };

  const int NS = (len + U - 1) / U;
  const int S  = NS + 2;

  // wave3 prologue: produce xg for slot 0; leave xrc = rows of slot 1
  float xrc[U], xrn[U];
  if (wave == 3) {
    #pragma unroll
    for (int j = 0; j < U; ++j) {
      int t = j; t = t > TT-1 ? TT-1 : t;
      xrc[j] = (lane < DDIM) ? xseq[(size_t)t*DDIM + lane] : 0.f;
    }
    #pragma unroll
    for (int j = 0; j < U; ++j) lds_xg[0][j][lane] = xgdot(xrc[j]);
    #pragma unroll
    for (int j = 0; j < U; ++j) {
      int t = U + j; t = t > TT-1 ? TT-1 : t;
      xrc[j] = (lane < DDIM) ? xseq[(size_t)t*DDIM + lane] : 0.f;
    }
  }
  __syncthreads();

  for (int s = 0; s < S; ++s) {
    const int p = s & 1, q = p ^ 1;
    if (wave == 0) {
      if (s < NS) {
        float xgv[U];
        #pragma unroll
        for (int j = 0; j < U; ++j) xgv[j] = lds_xg[p][j][lane];
        #pragma unroll
        for (int j = 0; j < U; ++j) {
          lstm_update(owndot(xgv[j]));
          if (gt == 0) lds_h0[p][j][ch] = hs;
        }
      }
    } else if (wave == 1) {
      if (s >= 1 && s <= NS) {
        float xin[U];
        #pragma unroll
        for (int j = 0; j < U; ++j) {     // ALL input-dots up front, off-chain
          const float4* hp = (const float4*)&lds_h0[q][j][0];
          float4 h0v = hp[0], h1v = hp[1], h2v = hp[2], h3v = hp[3];
          float hin[16] = {h0v.x,h0v.y,h0v.z,h0v.w, h1v.x,h1v.y,h1v.z,h1v.w,
                           h2v.x,h2v.y,h2v.z,h2v.w, h3v.x,h3v.y,h3v.z,h3v.w};
          xin[j] = indot(hin);
        }
        #pragma unroll
        for (int j = 0; j < U; ++j) {
          lstm_update(owndot(xin[j]));
          if (gt == 0) lds_h1[p][j][ch] = hs;
        }
      }
    } else if (wave == 2) {
      if (s >= 2) {
        float xin[U];
        #pragma unroll
        for (int j = 0; j < U; ++j) {
          const float4* hp = (const float4*)&lds_h1[q][j][0];
          float4 h0v = hp[0], h1v = hp[1], h2v = hp[2], h3v = hp[3];
          float hin[16] = {h0v.x,h0v.y,h0v.z,h0v.w, h1v.x,h1v.y,h1v.z,h1v.w,
                           h2v.x,h2v.y,h2v.z,h2v.w, h3v.x,h3v.y,h3v.z,h3v.w};
          xin[j] = indot(hin);
        }
        #pragma unroll
        for (int j = 0; j < U; ++j) {
          lstm_update(owndot(xin[j]));
          const int t = (s - 2)*U + j;
          if (t < len) {
            if (gt == 0) h2row[t*16 + ch] = hs;
            sum += hs; sq += hs*hs;
          }
        }
      }
    } else {
      // (a) issue loads for slot s+2 rows (consumed next slot's compute)
      #pragma unroll
      for (int j = 0; j < U; ++j) {
        int t = (s + 2)*U + j; t = t > TT-1 ? TT-1 : t;
        xrn[j] = (lane < DDIM) ? xseq[(size_t)t*DDIM + lane] : 0.f;
      }
      // (b) compute xg for slot s+1 from rows loaded last slot
      if (s + 1 < NS) {
        #pragma unroll
        for (int j = 0; j < U; ++j) lds_xg[q][j][lane] = xgdot(xrc[j]);
      }
      #pragma unroll
      for (int j = 0; j < U; ++j) xrc[j] = xrn[j];
    }
    __syncthreads();
  }

  for (int idx = len*16 + tid; idx < TT*16; idx += 256)
    h2row[idx] = 0.f;

  if (wave == 2 && gt == 0) {
    atomicAdd(&accum[ch],      sum);
    atomicAdd(&accum[16 + ch], sq);
  }
}

// Fold BN (training stats incl. padding zeros) + gamma/beta into FC.
__global__ void prep_k(const float* __restrict__ accum,
                       const float* __restrict__ gamma, const float* __restrict__ beta,
                       const float* __restrict__ fcw, const float* __restrict__ fcb,
                       float* __restrict__ coef)
{
  const int lane = threadIdx.x;
  const int o = lane >> 4, c = lane & 15;
  const float inv_n = 1.0f / NF;
  float mean = accum[c] * inv_n;
  float var  = accum[16 + c] * inv_n - mean*mean;
  float s  = gamma[c] * rsqrtf(var + 1e-5f);
  float tb = beta[c] - mean * s;
  float woc = fcw[o*16 + c];
  coef[lane] = s * woc;
  float term = tb * woc;
  #pragma unroll
  for (int off = 1; off < 16; off <<= 1) term += __shfl_xor(term, off, 16);
  if (c == 0) coef[64 + o] = fcb[o] + term;
}

__global__ __launch_bounds__(256) void finalize_k(
    const float* __restrict__ h2buf, const float* __restrict__ coef,
    float* __restrict__ out)
{
  const int r = blockIdx.x * 256 + threadIdx.x;
  const float4* hp = (const float4*)(h2buf + (size_t)r * 16);
  float4 v0 = hp[0], v1 = hp[1], v2 = hp[2], v3 = hp[3];
  float hv[16] = {v0.x,v0.y,v0.z,v0.w, v1.x,v1.y,v1.z,v1.w,
                  v2.x,v2.y,v2.z,v2.w, v3.x,v3.y,v3.z,v3.w};
  float4 o4;
  float* op = &o4.x;
  #pragma unroll
  for (int o = 0; o < 4; ++o) {
    float a = coef[64 + o];
    #pragma unroll
    for (int c = 0; c < 16; ++c) a += coef[o*16 + c] * hv[c];
    op[o] = a;
  }
  ((float4*)out)[r] = o4;
}

extern "C" void kernel_launch(void* const* d_in, const int* in_sizes, int n_in,
                              void* d_out, int out_size, void* d_ws, size_t ws_size,
                              hipStream_t stream)
{
  const float* x     = (const float*)d_in[0];
  const int* lengths = (const int*)d_in[1];
  const float* W_ih0 = (const float*)d_in[2];
  const float* W_hh0 = (const float*)d_in[3];
  const float* b_ih0 = (const float*)d_in[4];
  const float* b_hh0 = (const float*)d_in[5];
  const float* W_ih1 = (const float*)d_in[6];
  const float* W_hh1 = (const float*)d_in[7];
  const float* b_ih1 = (const float*)d_in[8];
  const float* b_hh1 = (const float*)d_in[9];
  const float* W_ih2 = (const float*)d_in[10];
  const float* W_hh2 = (const float*)d_in[11];
  const float* b_ih2 = (const float*)d_in[12];
  const float* b_hh2 = (const float*)d_in[13];
  const float* gamma = (const float*)d_in[14];
  const float* beta  = (const float*)d_in[15];
  const float* fcw   = (const float*)d_in[16];
  const float* fcb   = (const float*)d_in[17];
  float* out = (float*)d_out;

  float* ws    = (float*)d_ws;
  float* h2    = ws;                        // B*T*16 floats (32 MB)
  float* accum = ws + 8388608;              // 32 floats
  float* coef  = accum + 32;                // 68 floats

  hipLaunchKernelGGL(zero_accum_k, dim3(1), dim3(32), 0, stream, accum);
  hipLaunchKernelGGL(lstm_fused_k, dim3(256), dim3(256), 0, stream,
                     x, lengths, W_ih0, W_hh0, b_ih0, b_hh0,
                     W_ih1, W_hh1, b_ih1, b_hh1,
                     W_ih2, W_hh2, b_ih2, b_hh2, h2, accum);
  hipLaunchKernelGGL(prep_k, dim3(1), dim3(64), 0, stream,
                     accum, gamma, beta, fcw, fcb, coef);
  hipLaunchKernelGGL(finalize_k, dim3(2048), dim3(256), 0, stream, h2, coef, out);
}